// Round 15
// baseline (238.096 us; speedup 1.0000x reference)
//
#include <hip/hip_runtime.h>
#include <hip/hip_fp16.h>
#include <math.h>

#define N_NODES 50000
#define N_EDGES 800000
#define ET (N_EDGES + N_NODES)   // edges + self loops
#define IN_DIM 128
#define HEADS 8
#define NEG_SLOPE 0.2f

#define SCAN_TILE 256
#define NTILES ((N_NODES + SCAN_TILE - 1) / SCAN_TILE)   // 196
#define RC 13                     // cached score iterations (2 slots -> deg <= 26)

#define LIN1_WAVES (N_NODES / 8)                 // 6250
#define LIN1_BLOCKS ((LIN1_WAVES + 3) / 4)       // 1563
#define EB ((ET + 255) / 256)                    // 3321

__device__ __forceinline__ float lrelu(float v) { return v >= 0.f ? v : NEG_SLOPE * v; }

__device__ __forceinline__ float rdlane(float v, int l) {
    return __int_as_float(__builtin_amdgcn_readlane(__float_as_int(v), l));
}

// unpack 8 fp16 (16B) and FMA into a[8]
__device__ __forceinline__ void fma8h(const __half* __restrict__ base, float alpha, float* a) {
    uint4 u = *reinterpret_cast<const uint4*>(base);
    float2 f0 = __half22float2(*(const __half2*)&u.x);
    float2 f1 = __half22float2(*(const __half2*)&u.y);
    float2 f2 = __half22float2(*(const __half2*)&u.z);
    float2 f3 = __half22float2(*(const __half2*)&u.w);
    a[0] += f0.x * alpha; a[1] += f0.y * alpha;
    a[2] += f1.x * alpha; a[3] += f1.y * alpha;
    a[4] += f2.x * alpha; a[5] += f2.y * alpha;
    a[6] += f3.x * alpha; a[7] += f3.y * alpha;
}

// edge_index is int32 on device (validated round 4)
__device__ __forceinline__ void edge_nodes(const int* __restrict__ ei, int e, int& s, int& d) {
    if (e < N_EDGES) { s = ei[e]; d = ei[N_EDGES + e]; }
    else             { s = e - N_EDGES; d = s; }
}

// ---------------- fused: lin1 (blocks [0,LIN1_BLOCKS)) + count-with-pos (rest) ----------------

__global__ __launch_bounds__(256) void cl1_kernel(
    const int* __restrict__ ei, int* __restrict__ cnt, int* __restrict__ pos,
    const float* __restrict__ x, const float* __restrict__ W1,
    const float* __restrict__ a_src, const float* __restrict__ a_dst,
    __half* __restrict__ h1, float* __restrict__ ssrc, float* __restrict__ sdst)
{
    if (blockIdx.x >= LIN1_BLOCKS) {
        int i = (blockIdx.x - LIN1_BLOCKS) * 256 + threadIdx.x;
        if (i >= ET) return;
        int s, d; edge_nodes(ei, i, s, d);
        pos[i] = atomicAdd(&cnt[d], 1);      // pay the atomic once, keep the rank
        return;
    }
    int wid = threadIdx.x >> 6, t = threadIdx.x & 63;
    int g = blockIdx.x * 4 + wid;
    if (g >= LIN1_WAVES) return;
    int n0 = g * 8;

    float x0[8], x1[8];
    #pragma unroll
    for (int nn = 0; nn < 8; ++nn) {
        x0[nn] = x[(n0 + nn) * IN_DIM + t];
        x1[nn] = x[(n0 + nn) * IN_DIM + 64 + t];
    }
    float acc[8] = {0,0,0,0,0,0,0,0};
    #pragma unroll 8
    for (int k = 0; k < 64; ++k) {
        float w = W1[k * 64 + t];
        #pragma unroll
        for (int nn = 0; nn < 8; ++nn) acc[nn] += rdlane(x0[nn], k) * w;
    }
    #pragma unroll 8
    for (int k = 0; k < 64; ++k) {
        float w = W1[(k + 64) * 64 + t];
        #pragma unroll
        for (int nn = 0; nn < 8; ++nn) acc[nn] += rdlane(x1[nn], k) * w;
    }

    float av = a_src[t], bv = a_dst[t];
    #pragma unroll
    for (int nn = 0; nn < 8; ++nn) {
        int n = n0 + nn;
        h1[n * 64 + t] = __float2half(acc[nn]);
        float rs = acc[nn] * av, rd = acc[nn] * bv;
        rs += __shfl_xor(rs, 1); rs += __shfl_xor(rs, 2); rs += __shfl_xor(rs, 4);
        rd += __shfl_xor(rd, 1); rd += __shfl_xor(rd, 2); rd += __shfl_xor(rd, 4);
        if ((t & 7) == 0) { ssrc[n * 8 + (t >> 3)] = rs; sdst[n * 8 + (t >> 3)] = rd; }
    }
}

// ---------------- scans ----------------

__global__ __launch_bounds__(SCAN_TILE) void scanA_kernel(
    const int* __restrict__ cnt, int* __restrict__ row, int* __restrict__ aux)
{
    __shared__ int sh[SCAN_TILE];
    int t = threadIdx.x, i = blockIdx.x * SCAN_TILE + t;
    int v = (i < N_NODES) ? cnt[i] : 0;
    sh[t] = v;
    __syncthreads();
    #pragma unroll
    for (int off = 1; off < SCAN_TILE; off <<= 1) {
        int add = (t >= off) ? sh[t - off] : 0;
        __syncthreads();
        sh[t] += add;
        __syncthreads();
    }
    if (i < N_NODES) row[i] = sh[t] - v;
    if (t == SCAN_TILE - 1) aux[blockIdx.x] = sh[t];
}

__global__ __launch_bounds__(SCAN_TILE) void scanB_kernel(int* __restrict__ aux, int* __restrict__ row) {
    __shared__ int sh[SCAN_TILE];
    int t = threadIdx.x;
    int v = (t < NTILES) ? aux[t] : 0;
    sh[t] = v;
    __syncthreads();
    #pragma unroll
    for (int off = 1; off < SCAN_TILE; off <<= 1) {
        int add = (t >= off) ? sh[t - off] : 0;
        __syncthreads();
        sh[t] += add;
        __syncthreads();
    }
    if (t < NTILES) aux[t] = sh[t] - v;
    if (t == NTILES - 1) row[N_NODES] = sh[t];
}

__global__ __launch_bounds__(SCAN_TILE) void scanC_kernel(
    const int* __restrict__ aux, int* __restrict__ row)
{
    int i = blockIdx.x * SCAN_TILE + threadIdx.x;
    if (i >= N_NODES) return;
    row[i] += aux[i >> 8];
}

// atomic-free fill
__global__ void fill_kernel(const int* __restrict__ ei, const int* __restrict__ row,
                            const int* __restrict__ pos, int* __restrict__ adj)
{
    int i = blockIdx.x * blockDim.x + threadIdx.x;
    if (i >= ET) return;
    int s, d; edge_nodes(ei, i, s, d);
    adj[row[d] + pos[i]] = s;
}

// ---------------- layer-1 node kernel: 4 nodes per wave ----------------
// lane t: q = t>>4 (node), tt = t&15, slot = tt>>3 (2 slots), h = tt&7

__global__ __launch_bounds__(256) void l1_kernel(
    const int* __restrict__ row, const int* __restrict__ adj,
    const __half* __restrict__ h1, const float* __restrict__ s1, const float* __restrict__ t1,
    const float* __restrict__ b1, const float* __restrict__ W2,
    const float* __restrict__ as2, const float* __restrict__ ad2,
    __half* __restrict__ h2, float* __restrict__ s2, float* __restrict__ t2)
{
    int wid = threadIdx.x >> 6, t = threadIdx.x & 63;
    int q = t >> 4, tt = t & 15;
    int n = blockIdx.x * 16 + wid * 4 + q;
    int beg = row[n], end = row[n + 1];
    int slot = tt >> 3, h = tt & 7;
    float sd = t1[n * 8 + h];
    const int e0 = beg + slot;
    const int qb = q << 4;                        // quarter base lane

    // score pass: cache (sv, score)
    int   sv[RC];
    float p[RC];
    float m = -3e38f;
    #pragma unroll
    for (int it = 0; it < RC; ++it) {
        int e = e0 + it * 2;
        bool ok = e < end;
        int s = ok ? adj[e] : n;
        sv[it] = s;
        float v = ok ? lrelu(s1[s * 8 + h] + sd) : -3e38f;
        p[it] = v;
        m = fmaxf(m, v);
    }
    for (int e = e0 + RC * 2; e < end; e += 2)    // tail (deg > 26, ~1.4%)
        m = fmaxf(m, lrelu(s1[adj[e] * 8 + h] + sd));
    m = fmaxf(m, __shfl_xor(m, 8));

    float den = 0.f;
    #pragma unroll
    for (int it = 0; it < RC; ++it) {
        float pe = __expf(p[it] - m);             // empty slots -> 0
        p[it] = pe;
        den += pe;
    }
    for (int e = e0 + RC * 2; e < end; e += 2)
        den += __expf(lrelu(s1[adj[e] * 8 + h] + sd) - m);
    den += __shfl_xor(den, 8);
    float inv = 1.f / (den + 1e-16f);

    // aggregate: lane (slot,h) accumulates channels h*8..h*8+7
    float a[8] = {0,0,0,0,0,0,0,0};
    #pragma unroll
    for (int it = 0; it < RC; ++it) {
        int e = e0 + it * 2;
        if (e < end) fma8h(h1 + (size_t)sv[it] * 64 + h * 8, p[it] * inv, a);
    }
    for (int e = e0 + RC * 2; e < end; e += 2) {
        int s = adj[e];
        float alpha = __expf(lrelu(s1[s * 8 + h] + sd) - m) * inv;
        fma8h(h1 + (size_t)s * 64 + h * 8, alpha, a);
    }
    #pragma unroll
    for (int j = 0; j < 8; ++j) a[j] += __shfl_xor(a[j], 8);
    // lanes qb..qb+7 hold node's channels: lane qb+h reg j = ch h*8+j

    // redistribute: this lane needs channels tt+16c (c=0..3):
    //   ch k -> src lane qb + (k>>3), reg k&7;  (tt+16c)>>3 = (tt>>3)+2c, (tt+16c)&7 = tt&7
    float ha[4] = {0,0,0,0};
    int src0 = qb + (tt >> 3);
    #pragma unroll
    for (int j = 0; j < 8; ++j) {
        float v0 = __shfl(a[j], src0);
        float v1 = __shfl(a[j], src0 + 2);
        float v2 = __shfl(a[j], src0 + 4);
        float v3 = __shfl(a[j], src0 + 6);
        if ((tt & 7) == j) { ha[0] = v0; ha[1] = v1; ha[2] = v2; ha[3] = v3; }
    }

    // bias + ELU
    #pragma unroll
    for (int c = 0; c < 4; ++c) {
        float v = ha[c] + b1[tt + 16 * c];
        ha[c] = v > 0.f ? v : (__expf(v) - 1.f);
    }

    // fused lin2: channel k of node lives at lane qb + (k&15), reg k>>4
    float c2[4] = {0,0,0,0};
    #pragma unroll
    for (int cr = 0; cr < 4; ++cr) {
        #pragma unroll 8
        for (int kk = 0; kk < 16; ++kk) {
            float w = __shfl(ha[cr], qb + kk);
            int k = cr * 16 + kk;
            c2[0] += w * W2[k * 64 + tt];
            c2[1] += w * W2[k * 64 + tt + 16];
            c2[2] += w * W2[k * 64 + tt + 32];
            c2[3] += w * W2[k * 64 + tt + 48];
        }
    }
    #pragma unroll
    for (int c = 0; c < 4; ++c) h2[n * 64 + tt + 16 * c] = __float2half(c2[c]);

    // layer-2 scores (reduce within 16-lane quarter)
    float rs = 0.f, rd = 0.f;
    #pragma unroll
    for (int c = 0; c < 4; ++c) {
        rs += c2[c] * as2[tt + 16 * c];
        rd += c2[c] * ad2[tt + 16 * c];
    }
    #pragma unroll
    for (int mk = 8; mk >= 1; mk >>= 1) {
        rs += __shfl_xor(rs, mk);
        rd += __shfl_xor(rd, mk);
    }
    if (tt == 0) { s2[n] = rs; t2[n] = rd; }
}

// ---------------- layer-2 node kernel: 4 nodes per wave ----------------

__global__ __launch_bounds__(256) void l2_kernel(
    const int* __restrict__ row, const int* __restrict__ adj,
    const __half* __restrict__ h2, const float* __restrict__ s2, const float* __restrict__ t2,
    const float* __restrict__ b2, float* __restrict__ out)
{
    int wid = threadIdx.x >> 6, t = threadIdx.x & 63;
    int q = t >> 4, tt = t & 15;
    int n = blockIdx.x * 16 + wid * 4 + q;
    int beg = row[n], end = row[n + 1];
    int slot = tt >> 3, g = tt & 7;
    float sd = t2[n];
    const int e0 = beg + slot;

    int   sv[RC];
    float p[RC];
    float m = -3e38f;
    #pragma unroll
    for (int it = 0; it < RC; ++it) {
        int e = e0 + it * 2;
        bool ok = e < end;
        int s = ok ? adj[e] : n;
        sv[it] = s;
        float v = ok ? lrelu(s2[s] + sd) : -3e38f;
        p[it] = v;
        m = fmaxf(m, v);
    }
    for (int e = e0 + RC * 2; e < end; e += 2)
        m = fmaxf(m, lrelu(s2[adj[e]] + sd));
    m = fmaxf(m, __shfl_xor(m, 8));

    float den = 0.f;
    #pragma unroll
    for (int it = 0; it < RC; ++it) {
        float pe = __expf(p[it] - m);
        p[it] = pe;
        den += pe;
    }
    for (int e = e0 + RC * 2; e < end; e += 2)
        den += __expf(lrelu(s2[adj[e]] + sd) - m);
    den += __shfl_xor(den, 8);
    float inv = 1.f / (den + 1e-16f);

    float a[8] = {0,0,0,0,0,0,0,0};
    #pragma unroll
    for (int it = 0; it < RC; ++it) {
        int e = e0 + it * 2;
        if (e < end) fma8h(h2 + (size_t)sv[it] * 64 + g * 8, p[it] * inv, a);
    }
    for (int e = e0 + RC * 2; e < end; e += 2) {
        int s = adj[e];
        float alpha = __expf(lrelu(s2[s] + sd) - m) * inv;
        fma8h(h2 + (size_t)s * 64 + g * 8, alpha, a);
    }
    #pragma unroll
    for (int j = 0; j < 8; ++j) a[j] += __shfl_xor(a[j], 8);

    if (slot == 0) {
        float4 o0 = make_float4(a[0] + b2[g * 8 + 0], a[1] + b2[g * 8 + 1],
                                a[2] + b2[g * 8 + 2], a[3] + b2[g * 8 + 3]);
        float4 o1 = make_float4(a[4] + b2[g * 8 + 4], a[5] + b2[g * 8 + 5],
                                a[6] + b2[g * 8 + 6], a[7] + b2[g * 8 + 7]);
        float4* op = (float4*)(out + (size_t)n * 64 + g * 8);
        op[0] = o0; op[1] = o1;
    }
}

extern "C" void kernel_launch(void* const* d_in, const int* in_sizes, int n_in,
                              void* d_out, int out_size, void* d_ws, size_t ws_size,
                              hipStream_t stream)
{
    const float* x   = (const float*)d_in[0];
    const int* ei    = (const int*)d_in[1];
    const float* W1  = (const float*)d_in[2];
    const float* as1 = (const float*)d_in[3];
    const float* ad1 = (const float*)d_in[4];
    const float* b1  = (const float*)d_in[5];
    const float* W2  = (const float*)d_in[6];
    const float* as2 = (const float*)d_in[7];
    const float* ad2 = (const float*)d_in[8];
    const float* b2  = (const float*)d_in[9];
    float* out = (float*)d_out;

    char* wsb = (char*)d_ws;
    __half* h1  = (__half*)wsb;                       // N*64 fp16
    __half* h2  = h1 + (size_t)N_NODES * 64;          // N*64 fp16
    float*  s1  = (float*)(h2 + (size_t)N_NODES * 64);// N*8
    float*  t1  = s1 + N_NODES * 8;                   // N*8
    float*  s2  = t1 + N_NODES * 8;                   // N
    float*  t2  = s2 + N_NODES;                       // N
    int*    cnt = (int*)(t2 + N_NODES);               // N
    int*    rowp = cnt + N_NODES;                     // N+1
    int*    aux  = rowp + N_NODES + 1;                // NTILES
    int*    adj  = aux + NTILES;                      // ET
    int*    pos  = adj + ET;                          // ET

    hipMemsetAsync(cnt, 0, N_NODES * sizeof(int), stream);

    cl1_kernel<<<LIN1_BLOCKS + EB, 256, 0, stream>>>(ei, cnt, pos, x, W1, as1, ad1, h1, s1, t1);

    scanA_kernel<<<NTILES, SCAN_TILE, 0, stream>>>(cnt, rowp, aux);
    scanB_kernel<<<1, SCAN_TILE, 0, stream>>>(aux, rowp);
    scanC_kernel<<<NTILES, SCAN_TILE, 0, stream>>>(aux, rowp);
    fill_kernel<<<EB, 256, 0, stream>>>(ei, rowp, pos, adj);

    l1_kernel<<<N_NODES / 16, 256, 0, stream>>>(rowp, adj, h1, s1, t1,
                                                b1, W2, as2, ad2, h2, s2, t2);

    l2_kernel<<<N_NODES / 16, 256, 0, stream>>>(rowp, adj, h2, s2, t2, b2, out);
}